// Round 2
// baseline (248.731 us; speedup 1.0000x reference)
//
#include <hip/hip_runtime.h>

#define Bx 2
#define Sx 4096
#define Ex 1024
#define Hx 16
#define DHx 64
#define Wwin 512

typedef unsigned short u16;
typedef __attribute__((ext_vector_type(8))) short bf16x8;
typedef __attribute__((ext_vector_type(4))) float f32x4;
typedef __attribute__((ext_vector_type(4))) unsigned short u16x4;

// RTNE float -> bf16 (finite inputs)
__device__ __forceinline__ u16 f2b(float f) {
  unsigned u = __builtin_bit_cast(unsigned, f);
  unsigned r = (u + 0x7FFFu + ((u >> 16) & 1u)) >> 16;
  return (u16)r;
}

// async global->LDS, 16B per lane; LDS dest = wave-uniform base + lane*16
__device__ __forceinline__ void gload_lds16(const void* g, void* l) {
  __builtin_amdgcn_global_load_lds(
      (const __attribute__((address_space(1))) void*)g,
      (__attribute__((address_space(3))) void*)l, 16, 0, 0);
}

// ---------------- cast x (f32 -> bf16), vectorized ----------------
__global__ __launch_bounds__(256) void cast_x_kernel(const float* __restrict__ x,
                                                     u16* __restrict__ xb) {
  long idx = ((long)blockIdx.x * 256 + threadIdx.x) * 4;
  float4 v = *(const float4*)(x + idx);
  u16x4 o;
  o[0] = f2b(v.x); o[1] = f2b(v.y); o[2] = f2b(v.z); o[3] = f2b(v.w);
  *(u16x4*)(xb + idx) = o;
}

// ------------- pack weights: Wcat_t[1152][1024], Wo_t[1024][1024] -------------
// thread per INPUT element (coalesced reads, scattered 2B writes absorbed by L2)
__global__ __launch_bounds__(256) void pack_w_kernel(const float* __restrict__ Wq,
                                                     const float* __restrict__ Wk,
                                                     const float* __restrict__ Wv,
                                                     const float* __restrict__ Wo,
                                                     u16* __restrict__ wcat,
                                                     u16* __restrict__ wot) {
  int idx = blockIdx.x * 256 + threadIdx.x;
  if (idx < 1048576) {                       // Wq (E, H*DH)
    int e = idx >> 10, n = idx & 1023;
    wcat[n * 1024 + e] = f2b(Wq[idx]);
  } else if (idx < 1048576 + 65536) {        // Wk (E, 64)
    int i2 = idx - 1048576;
    int e = i2 >> 6, d = i2 & 63;
    wcat[(1024 + d) * 1024 + e] = f2b(Wk[i2]);
  } else if (idx < 1048576 + 131072) {       // Wv (E, 64)
    int i2 = idx - (1048576 + 65536);
    int e = i2 >> 6, d = i2 & 63;
    wcat[(1088 + d) * 1024 + e] = f2b(Wv[i2]);
  } else {                                   // Wo (H*DH, E) -> (E, H*DH)
    int i2 = idx - (1048576 + 131072);
    int hd = i2 >> 10, e = i2 & 1023;
    wot[e * 1024 + hd] = f2b(Wo[i2]);
  }
}

// ---------------- GEMM: C(M,N) = A(M,K) * Bt(N,K)^T, bf16 in, f32 acc ----------------
// 128x128 tile, BK=64, 4 waves (2x2 of 64x64), global_load_lds staging,
// XOR-swizzled LDS (chunk c at phys c^(row&7)) to kill 128B-row bank conflicts.
template <typename OutT>
__global__ __launch_bounds__(256) void gemm_bt_kernel(const u16* __restrict__ A,
                                                      const u16* __restrict__ Bt,
                                                      OutT* __restrict__ C,
                                                      int M, int N, int K) {
  __shared__ u16 As[128 * 64];
  __shared__ u16 Bs[128 * 64];
  const int tid = threadIdx.x;
  const int lane = tid & 63, wave = tid >> 6;
  const int ll = lane & 15, gl = lane >> 4;
  const int wr = wave >> 1, wc = wave & 1;
  const long m0 = (long)blockIdx.x * 128;
  const long n0 = (long)blockIdx.y * 128;
  const int segrow = lane >> 3, cph = lane & 7;

  f32x4 acc[4][4] = {};

  for (int kb = 0; kb < K; kb += 64) {
    __syncthreads();   // protect LDS reuse (WAR vs previous compute)
#pragma unroll
    for (int q = 0; q < 4; ++q) {
      int s = wave * 4 + q;          // 16 segments of 1KB
      int row = s * 8 + segrow;      // 0..127
      int clog = cph ^ (row & 7);    // pre-swizzled global source
      gload_lds16(A + (m0 + row) * K + kb + clog * 8, (char*)As + s * 1024);
      gload_lds16(Bt + (n0 + row) * K + kb + clog * 8, (char*)Bs + s * 1024);
    }
    __syncthreads();   // drains vmcnt for global_load_lds
#pragma unroll
    for (int kx = 0; kx < 2; ++kx) {
      bf16x8 af[4], bfr[4];
#pragma unroll
      for (int rg = 0; rg < 4; ++rg) {
        int row = wr * 64 + rg * 16 + ll;
        int c = kx * 4 + gl;
        af[rg] = *(const bf16x8*)&As[row * 64 + ((c ^ (row & 7)) << 3)];
      }
#pragma unroll
      for (int cg = 0; cg < 4; ++cg) {
        int row = wc * 64 + cg * 16 + ll;
        int c = kx * 4 + gl;
        bfr[cg] = *(const bf16x8*)&Bs[row * 64 + ((c ^ (row & 7)) << 3)];
      }
#pragma unroll
      for (int rg = 0; rg < 4; ++rg)
#pragma unroll
        for (int cg = 0; cg < 4; ++cg)
          acc[rg][cg] = __builtin_amdgcn_mfma_f32_16x16x32_bf16(af[rg], bfr[cg],
                                                                acc[rg][cg], 0, 0, 0);
    }
  }
#pragma unroll
  for (int rg = 0; rg < 4; ++rg)
#pragma unroll
    for (int cg = 0; cg < 4; ++cg)
#pragma unroll
      for (int r = 0; r < 4; ++r) {
        long row = m0 + wr * 64 + rg * 16 + gl * 4 + r;
        long col = n0 + wc * 64 + cg * 16 + ll;
        if constexpr (sizeof(OutT) == 2)
          C[row * (long)N + col] = f2b(acc[rg][cg][r]);
        else
          C[row * (long)N + col] = acc[rg][cg][r];
      }
}

// ---------------- V transpose: vt[b][dh=64][S] <- qkvb[.., 1088+dh] ----------------
__global__ __launch_bounds__(256) void vt_transpose_kernel(const u16* __restrict__ qkvb,
                                                           u16* __restrict__ vt) {
  __shared__ u16 T[64 * 65];
  const int blk = blockIdx.x;
  const int b = blk >> 6;
  const int j0 = (blk & 63) * 64;
  const int tid = threadIdx.x;
#pragma unroll
  for (int rep = 0; rep < 16; ++rep) {
    int idx = rep * 256 + tid;
    int jj = idx >> 6, dd = idx & 63;
    T[dd * 65 + jj] = qkvb[((long)b * Sx + j0 + jj) * 1152 + 1088 + dd];
  }
  __syncthreads();
#pragma unroll
  for (int rep = 0; rep < 16; ++rep) {
    int idx = rep * 256 + tid;
    int dd = idx >> 6, jj = idx & 63;
    vt[((long)b * 64 + dd) * Sx + j0 + jj] = T[dd * 65 + jj];
  }
}

// ---------------- sliding-window attention ----------------
// block = (b, 128-query tile, head); 4 waves x 32 queries; 64-key chunks;
// online softmax; K/Vt staged in swizzled LDS; P via per-wave LDS (no barrier).
__global__ __launch_bounds__(256) void attn_kernel(const u16* __restrict__ qkv,
                                                   const u16* __restrict__ vt,
                                                   const float* __restrict__ bias,
                                                   u16* __restrict__ attnb) {
  __shared__ u16 Ks[64 * 64];    // [key][dh]  swizzled
  __shared__ u16 Vts[64 * 64];   // [dh][key]  swizzled
  __shared__ u16 Pb[4][32 * 64]; // per-wave P, swizzled
  __shared__ float biasS[512];

  const int bid = blockIdx.x;
  const int h = bid & 15;
  const int qt = (bid >> 4) & 31;
  const int b = bid >> 9;
  const int q0 = qt * 128;
  const long bS = (long)b * Sx;

  const int tid = threadIdx.x;
  const int lane = tid & 63, wave = tid >> 6;
  const int ll = lane & 15, gl = lane >> 4;
  const int wq0 = q0 + wave * 32;
  const int segrow = lane >> 3, cph = lane & 7;

  for (int i = tid; i < 512; i += 256) biasS[i] = bias[h * 512 + i];

  bf16x8 qf[2][2];  // [q rowgroup][k-step], Q kept in registers
#pragma unroll
  for (int rg = 0; rg < 2; ++rg)
#pragma unroll
    for (int kx = 0; kx < 2; ++kx)
      qf[rg][kx] = *(const bf16x8*)&qkv[(bS + wq0 + rg * 16 + ll) * 1152 +
                                        h * 64 + kx * 32 + gl * 8];

  f32x4 oacc[2][4] = {};
  float mrow[2][4], lrow[2][4];
#pragma unroll
  for (int rg = 0; rg < 2; ++rg)
#pragma unroll
    for (int r = 0; r < 4; ++r) { mrow[rg][r] = -3e38f; lrow[rg][r] = 0.f; }

  u16* Pw = &Pb[wave][0];

  const int kb_start = (q0 - 512) > 0 ? (q0 - 512) : 0;
  const int kb_end = q0 + 64;  // inclusive
  for (int kb = kb_start; kb <= kb_end; kb += 64) {
#pragma unroll
    for (int q = 0; q < 2; ++q) {
      int s = wave * 2 + q;
      int rrow = s * 8 + segrow;           // key for Ks, dh for Vts
      int clog = cph ^ (rrow & 7);
      gload_lds16(qkv + (bS + kb + rrow) * 1152 + 1024 + clog * 8, (char*)Ks + s * 1024);
      gload_lds16(vt + ((long)b * 64 + rrow) * Sx + kb + clog * 8, (char*)Vts + s * 1024);
    }
    __syncthreads();
    const bool active = (kb <= wq0 + 31) && (kb + 63 >= wq0 - 511);
    if (active) {
      // S = Q K^T  (rows=q, cols=key)
      f32x4 sacc[2][4] = {};
#pragma unroll
      for (int kx = 0; kx < 2; ++kx) {
        bf16x8 kf[4];
#pragma unroll
        for (int cg = 0; cg < 4; ++cg) {
          int key = cg * 16 + ll;
          int c = kx * 4 + gl;
          kf[cg] = *(const bf16x8*)&Ks[key * 64 + ((c ^ (key & 7)) << 3)];
        }
#pragma unroll
        for (int rg = 0; rg < 2; ++rg)
#pragma unroll
          for (int cg = 0; cg < 4; ++cg)
            sacc[rg][cg] = __builtin_amdgcn_mfma_f32_16x16x32_bf16(qf[rg][kx], kf[cg],
                                                                   sacc[rg][cg], 0, 0, 0);
      }
#pragma unroll
      for (int rg = 0; rg < 2; ++rg) {
        float cmax[4] = {-3e38f, -3e38f, -3e38f, -3e38f};
#pragma unroll
        for (int cg = 0; cg < 4; ++cg)
#pragma unroll
          for (int r = 0; r < 4; ++r) {
            int i = wq0 + rg * 16 + gl * 4 + r;   // global query
            int j = kb + cg * 16 + ll;            // global key
            int d = i - j;
            int dc = d < 0 ? 0 : (d > 511 ? 511 : d);
            float sc = (d >= 0 && d < 512) ? fmaf(sacc[rg][cg][r], 0.125f, biasS[dc])
                                           : -1e30f;
            sacc[rg][cg][r] = sc;
            cmax[r] = fmaxf(cmax[r], sc);
          }
#pragma unroll
        for (int r = 0; r < 4; ++r) {
          cmax[r] = fmaxf(cmax[r], __shfl_xor(cmax[r], 1));
          cmax[r] = fmaxf(cmax[r], __shfl_xor(cmax[r], 2));
          cmax[r] = fmaxf(cmax[r], __shfl_xor(cmax[r], 4));
          cmax[r] = fmaxf(cmax[r], __shfl_xor(cmax[r], 8));
          float mnew = fmaxf(mrow[rg][r], cmax[r]);
          float f = __expf(mrow[rg][r] - mnew);
          mrow[rg][r] = mnew;
          lrow[rg][r] *= f;
#pragma unroll
          for (int cg = 0; cg < 4; ++cg) oacc[rg][cg][r] *= f;
        }
        float csum[4] = {0.f, 0.f, 0.f, 0.f};
#pragma unroll
        for (int cg = 0; cg < 4; ++cg)
#pragma unroll
          for (int r = 0; r < 4; ++r) {
            float p = __expf(sacc[rg][cg][r] - mrow[rg][r]);
            sacc[rg][cg][r] = p;
            csum[r] += p;
          }
#pragma unroll
        for (int r = 0; r < 4; ++r) {
          csum[r] += __shfl_xor(csum[r], 1);
          csum[r] += __shfl_xor(csum[r], 2);
          csum[r] += __shfl_xor(csum[r], 4);
          csum[r] += __shfl_xor(csum[r], 8);
          lrow[rg][r] += csum[r];
        }
        // P -> per-wave LDS (bf16, swizzled); same-wave RAW handled by waitcnt
#pragma unroll
        for (int cg = 0; cg < 4; ++cg)
#pragma unroll
          for (int r = 0; r < 4; ++r) {
            int row = rg * 16 + gl * 4 + r;
            int col = cg * 16 + ll;
            Pw[row * 64 + (((col >> 3) ^ (row & 7)) << 3) + (col & 7)] =
                f2b(sacc[rg][cg][r]);
          }
      }
      // O += P V
#pragma unroll
      for (int kx = 0; kx < 2; ++kx) {
        bf16x8 pf[2], vf[4];
#pragma unroll
        for (int rg = 0; rg < 2; ++rg) {
          int row = rg * 16 + ll;
          int c = kx * 4 + gl;
          pf[rg] = *(const bf16x8*)&Pw[row * 64 + ((c ^ (row & 7)) << 3)];
        }
#pragma unroll
        for (int cg = 0; cg < 4; ++cg) {
          int dh = cg * 16 + ll;
          int c = kx * 4 + gl;
          vf[cg] = *(const bf16x8*)&Vts[dh * 64 + ((c ^ (dh & 7)) << 3)];
        }
#pragma unroll
        for (int rg = 0; rg < 2; ++rg)
#pragma unroll
          for (int cg = 0; cg < 4; ++cg)
            oacc[rg][cg] = __builtin_amdgcn_mfma_f32_16x16x32_bf16(pf[rg], vf[cg],
                                                                   oacc[rg][cg], 0, 0, 0);
      }
    }
    __syncthreads();  // protect Ks/Vts before next chunk's staging
  }
  // epilogue: O / l -> attnb (bf16), layout (token, h*64+dh)
#pragma unroll
  for (int rg = 0; rg < 2; ++rg)
#pragma unroll
    for (int r = 0; r < 4; ++r) {
      float inv = 1.0f / lrow[rg][r];
      long i = wq0 + rg * 16 + gl * 4 + r;
#pragma unroll
      for (int cg = 0; cg < 4; ++cg)
        attnb[(bS + i) * 1024 + h * 64 + cg * 16 + ll] = f2b(oacc[rg][cg][r] * inv);
    }
}

extern "C" void kernel_launch(void* const* d_in, const int* in_sizes, int n_in,
                              void* d_out, int out_size, void* d_ws, size_t ws_size,
                              hipStream_t stream) {
  const float* x    = (const float*)d_in[0];
  const float* bias = (const float*)d_in[1];
  const float* Wq   = (const float*)d_in[2];
  const float* Wk   = (const float*)d_in[3];
  const float* Wv   = (const float*)d_in[4];
  const float* Wo   = (const float*)d_in[5];
  float* out = (float*)d_out;

  // workspace layout (39.25 MB total); attnb ALIASES xb (xb dead after GEMM1)
  u16* xb    = (u16*)d_ws;                       // 8192x1024      (16 MB)
  u16* wcat  = xb    + (size_t)8192 * 1024;      // 1152x1024 (N,K) (2.25 MB)
  u16* wot   = wcat  + (size_t)1152 * 1024;      // 1024x1024 (N,K) (2 MB)
  u16* qkvb  = wot   + (size_t)1024 * 1024;      // 8192x1152      (18 MB)
  u16* vtb   = qkvb  + (size_t)8192 * 1152;      // 2x64x4096      (1 MB)
  u16* attnb = xb;                               // reuse xb       (16 MB)

  cast_x_kernel<<<8192, 256, 0, stream>>>(x, xb);
  pack_w_kernel<<<8704, 256, 0, stream>>>(Wq, Wk, Wv, Wo, wcat, wot);
  gemm_bt_kernel<u16><<<dim3(64, 9), 256, 0, stream>>>(xb, wcat, qkvb, 8192, 1152, 1024);
  vt_transpose_kernel<<<128, 256, 0, stream>>>(qkvb, vtb);
  attn_kernel<<<1024, 256, 0, stream>>>(qkvb, vtb, bias, attnb);
  gemm_bt_kernel<float><<<dim3(64, 8), 256, 0, stream>>>(attnb, wot, out, 8192, 1024, 1024);
}

// Round 6
// 231.006 us; speedup vs baseline: 1.0767x; 1.0767x over previous
//
#include <hip/hip_runtime.h>

#define Bx 2
#define Sx 4096
#define Ex 1024
#define Hx 16
#define DHx 64
#define Wwin 512

typedef unsigned short u16;
typedef unsigned int u32;
typedef __attribute__((ext_vector_type(8))) short bf16x8;
typedef __attribute__((ext_vector_type(4))) float f32x4;
typedef __attribute__((ext_vector_type(4))) unsigned short u16x4;

// RTNE float -> bf16 (finite inputs)
__device__ __forceinline__ u16 f2b(float f) {
  unsigned u = __builtin_bit_cast(unsigned, f);
  unsigned r = (u + 0x7FFFu + ((u >> 16) & 1u)) >> 16;
  return (u16)r;
}

// packed f32x2 -> bf16x2 (RTNE), single instruction
__device__ __forceinline__ u32 cvt_pk_bf16(float lo, float hi) {
  u32 r;
  asm("v_cvt_pk_bf16_f32 %0, %1, %2" : "=v"(r) : "v"(lo), "v"(hi));
  return r;
}

// async global->LDS, 16B per lane; LDS dest = wave-uniform base + lane*16
__device__ __forceinline__ void gload_lds16(const void* g, void* l) {
  __builtin_amdgcn_global_load_lds(
      (const __attribute__((address_space(1))) void*)g,
      (__attribute__((address_space(3))) void*)l, 16, 0, 0);
}

// ---------------- cast x (f32 -> bf16), vectorized ----------------
__global__ __launch_bounds__(256) void cast_x_kernel(const float* __restrict__ x,
                                                     u16* __restrict__ xb) {
  long idx = ((long)blockIdx.x * 256 + threadIdx.x) * 4;
  float4 v = *(const float4*)(x + idx);
  u16x4 o;
  o[0] = f2b(v.x); o[1] = f2b(v.y); o[2] = f2b(v.z); o[3] = f2b(v.w);
  *(u16x4*)(xb + idx) = o;
}

// ------------- pack weights: Wcat_t[1152][1024], Wo_t[1024][1024] -------------
__global__ __launch_bounds__(256) void pack_w_kernel(const float* __restrict__ Wq,
                                                     const float* __restrict__ Wk,
                                                     const float* __restrict__ Wv,
                                                     const float* __restrict__ Wo,
                                                     u16* __restrict__ wcat,
                                                     u16* __restrict__ wot) {
  int idx = blockIdx.x * 256 + threadIdx.x;
  if (idx < 1048576) {                       // Wq (E, H*DH)
    int e = idx >> 10, n = idx & 1023;
    wcat[n * 1024 + e] = f2b(Wq[idx]);
  } else if (idx < 1048576 + 65536) {        // Wk (E, 64)
    int i2 = idx - 1048576;
    int e = i2 >> 6, d = i2 & 63;
    wcat[(1024 + d) * 1024 + e] = f2b(Wk[i2]);
  } else if (idx < 1048576 + 131072) {       // Wv (E, 64)
    int i2 = idx - (1048576 + 65536);
    int e = i2 >> 6, d = i2 & 63;
    wcat[(1088 + d) * 1024 + e] = f2b(Wv[i2]);
  } else {                                   // Wo (H*DH, E) -> (E, H*DH)
    int i2 = idx - (1048576 + 131072);
    int hd = i2 >> 10, e = i2 & 1023;
    wot[e * 1024 + hd] = f2b(Wo[i2]);
  }
}

// ---------------- GEMM: C(M,N) = A(M,K) * Bt(N,K)^T, bf16 in, f32 acc ----------------
template <typename OutT>
__global__ __launch_bounds__(256) void gemm_bt_kernel(const u16* __restrict__ A,
                                                      const u16* __restrict__ Bt,
                                                      OutT* __restrict__ C,
                                                      int M, int N, int K) {
  __shared__ u16 As[128 * 64];
  __shared__ u16 Bs[128 * 64];
  const int tid = threadIdx.x;
  const int lane = tid & 63, wave = tid >> 6;
  const int ll = lane & 15, gl = lane >> 4;
  const int wr = wave >> 1, wc = wave & 1;
  const long m0 = (long)blockIdx.x * 128;
  const long n0 = (long)blockIdx.y * 128;
  const int segrow = lane >> 3, cph = lane & 7;

  f32x4 acc[4][4] = {};

  for (int kb = 0; kb < K; kb += 64) {
    __syncthreads();
#pragma unroll
    for (int q = 0; q < 4; ++q) {
      int s = wave * 4 + q;
      int row = s * 8 + segrow;
      int clog = cph ^ (row & 7);
      gload_lds16(A + (m0 + row) * K + kb + clog * 8, (char*)As + s * 1024);
      gload_lds16(Bt + (n0 + row) * K + kb + clog * 8, (char*)Bs + s * 1024);
    }
    __syncthreads();
#pragma unroll
    for (int kx = 0; kx < 2; ++kx) {
      bf16x8 af[4], bfr[4];
#pragma unroll
      for (int rg = 0; rg < 4; ++rg) {
        int row = wr * 64 + rg * 16 + ll;
        int c = kx * 4 + gl;
        af[rg] = *(const bf16x8*)&As[row * 64 + ((c ^ (row & 7)) << 3)];
      }
#pragma unroll
      for (int cg = 0; cg < 4; ++cg) {
        int row = wc * 64 + cg * 16 + ll;
        int c = kx * 4 + gl;
        bfr[cg] = *(const bf16x8*)&Bs[row * 64 + ((c ^ (row & 7)) << 3)];
      }
#pragma unroll
      for (int rg = 0; rg < 4; ++rg)
#pragma unroll
        for (int cg = 0; cg < 4; ++cg)
          acc[rg][cg] = __builtin_amdgcn_mfma_f32_16x16x32_bf16(af[rg], bfr[cg],
                                                                acc[rg][cg], 0, 0, 0);
    }
  }
#pragma unroll
  for (int rg = 0; rg < 4; ++rg)
#pragma unroll
    for (int cg = 0; cg < 4; ++cg)
#pragma unroll
      for (int r = 0; r < 4; ++r) {
        long row = m0 + wr * 64 + rg * 16 + gl * 4 + r;
        long col = n0 + wc * 64 + cg * 16 + ll;
        if constexpr (sizeof(OutT) == 2)
          C[row * (long)N + col] = f2b(acc[rg][cg][r]);
        else
          C[row * (long)N + col] = acc[rg][cg][r];
      }
}

// ---------------- V transpose: vt[b][dh=64][S] <- qkvb[.., 1088+dh] ----------------
__global__ __launch_bounds__(256) void vt_transpose_kernel(const u16* __restrict__ qkvb,
                                                           u16* __restrict__ vt) {
  __shared__ u16 T[64 * 65];
  const int blk = blockIdx.x;
  const int b = blk >> 6;
  const int j0 = (blk & 63) * 64;
  const int tid = threadIdx.x;
#pragma unroll
  for (int rep = 0; rep < 16; ++rep) {
    int idx = rep * 256 + tid;
    int jj = idx >> 6, dd = idx & 63;
    T[dd * 65 + jj] = qkvb[((long)b * Sx + j0 + jj) * 1152 + 1088 + dd];
  }
  __syncthreads();
#pragma unroll
  for (int rep = 0; rep < 16; ++rep) {
    int idx = rep * 256 + tid;
    int dd = idx >> 6, jj = idx & 63;
    vt[((long)b * 64 + dd) * Sx + j0 + jj] = T[dd * 65 + jj];
  }
}

// ---------------- sliding-window attention (v2) ----------------
// 4 independent waves x 32 queries; no barriers in main loop; K/V frags loaded
// global->reg (L1/L2 reuse across heads); fixed-M exp2 softmax (no max/rescale/
// reduce); row-sum l via ones-column MFMA; P via per-wave swizzled LDS.
__global__ __launch_bounds__(256) void attn_kernel(const u16* __restrict__ qkv,
                                                   const u16* __restrict__ vt,
                                                   const float* __restrict__ bias,
                                                   u16* __restrict__ attnb) {
  __shared__ u16 Pb[4][32 * 64];   // per-wave P, swizzled
  __shared__ float bias2S[512];    // bias*log2e - 24

  // XCD remap: put all 16 heads of a query tile (shared K/V) on one XCD's L2
  const int bid0 = blockIdx.x;
  const int bid = (bid0 & 7) * 128 + (bid0 >> 3);
  const int h = bid & 15;
  const int qt = (bid >> 4) & 31;
  const int b = bid >> 9;
  const int q0 = qt * 128;
  const long bS = (long)b * Sx;

  const int tid = threadIdx.x;
  const int lane = tid & 63, wave = tid >> 6;
  const int ll = lane & 15, gl = lane >> 4;
  const int wq0 = q0 + wave * 32;

  for (int i = tid; i < 512; i += 256)
    bias2S[i] = fmaf(bias[h * 512 + i], 1.4426950408889634f, -24.0f);
  __syncthreads();

  const float C1 = 0.125f * 1.4426950408889634f;  // scale * log2e

  bf16x8 qf[2][2];  // [q rowgroup][k-step]
#pragma unroll
  for (int rg = 0; rg < 2; ++rg)
#pragma unroll
    for (int kx = 0; kx < 2; ++kx)
      qf[rg][kx] = *(const bf16x8*)&qkv[(bS + wq0 + rg * 16 + ll) * 1152 +
                                        h * 64 + kx * 32 + gl * 8];

  // ones-column fragment for l (V^T row 64 == 1, rows 65..79 == 0)
  u16 ov = (ll == 0) ? (u16)0x3F80 : (u16)0;
  bf16x8 vones;
#pragma unroll
  for (int i = 0; i < 8; ++i) vones[i] = (short)ov;

  f32x4 oacc[2][4] = {};
  f32x4 lacc[2] = {};

  u16* Pw = &Pb[wave][0];

  const int kb_start = (wq0 > 511) ? ((wq0 - 511) & ~63) : 0;
  const int kb_last = (wq0 + 31) & ~63;
  for (int kb = kb_start; kb <= kb_last; kb += 64) {
    // ---- K/V fragment gathers (reg-staged, L1/L2-served) ----
    bf16x8 kf[2][4], vfr[2][4];
#pragma unroll
    for (int kx = 0; kx < 2; ++kx)
#pragma unroll
      for (int cg = 0; cg < 4; ++cg) {
        kf[kx][cg] = *(const bf16x8*)&qkv[(bS + kb + cg * 16 + ll) * 1152 + 1024 +
                                          kx * 32 + gl * 8];
        vfr[kx][cg] = *(const bf16x8*)&vt[((long)b * 64 + cg * 16 + ll) * Sx + kb +
                                          kx * 32 + gl * 8];
      }
    // ---- S = Q K^T ----
    f32x4 sacc[2][4] = {};
#pragma unroll
    for (int kx = 0; kx < 2; ++kx)
#pragma unroll
      for (int rg = 0; rg < 2; ++rg)
#pragma unroll
        for (int cg = 0; cg < 4; ++cg)
          sacc[rg][cg] = __builtin_amdgcn_mfma_f32_16x16x32_bf16(qf[rg][kx], kf[kx][cg],
                                                                 sacc[rg][cg], 0, 0, 0);
    // ---- fixed-M softmax: p = exp2(qk*C1 + bias2[d]) ----
    const int dbase = (wq0 - kb) + gl * 4 - ll;  // d = dbase + rg*16 + r - cg*16
    const bool full = (kb - wq0 >= -480) && (kb - wq0 <= -64);
    if (full) {
      const float* bp = bias2S + dbase;
#pragma unroll
      for (int rg = 0; rg < 2; ++rg)
#pragma unroll
        for (int cg = 0; cg < 4; ++cg)
#pragma unroll
          for (int r = 0; r < 4; ++r)
            sacc[rg][cg][r] =
                __builtin_exp2f(fmaf(sacc[rg][cg][r], C1, bp[rg * 16 + r - cg * 16]));
    } else {
#pragma unroll
      for (int rg = 0; rg < 2; ++rg)
#pragma unroll
        for (int cg = 0; cg < 4; ++cg)
#pragma unroll
          for (int r = 0; r < 4; ++r) {
            int d = dbase + rg * 16 + r - cg * 16;
            int dc = d < 0 ? 0 : (d > 511 ? 511 : d);
            float p = __builtin_exp2f(fmaf(sacc[rg][cg][r], C1, bias2S[dc]));
            sacc[rg][cg][r] = ((unsigned)d < 512u) ? p : 0.0f;
          }
    }
    // ---- P -> per-wave LDS (bf16, swizzled), packed converts ----
#pragma unroll
    for (int rg = 0; rg < 2; ++rg)
#pragma unroll
      for (int cg = 0; cg < 4; ++cg)
#pragma unroll
        for (int rp = 0; rp < 2; ++rp) {
          u32 pk = cvt_pk_bf16(sacc[rg][cg][2 * rp], sacc[rg][cg][2 * rp + 1]);
          int row0 = rg * 16 + gl * 4 + 2 * rp;
          int col = cg * 16 + ll;
          Pw[row0 * 64 + (((col >> 3) ^ (row0 & 7)) << 3) + (col & 7)] = (u16)pk;
          int row1 = row0 + 1;
          Pw[row1 * 64 + (((col >> 3) ^ (row1 & 7)) << 3) + (col & 7)] = (u16)(pk >> 16);
        }
    // ---- O += P V ; l += P * 1 ----
#pragma unroll
    for (int kx = 0; kx < 2; ++kx) {
      bf16x8 pf[2];
#pragma unroll
      for (int rg = 0; rg < 2; ++rg) {
        int row = rg * 16 + ll;
        int c = kx * 4 + gl;
        pf[rg] = *(const bf16x8*)&Pw[row * 64 + ((c ^ (row & 7)) << 3)];
      }
#pragma unroll
      for (int rg = 0; rg < 2; ++rg) {
#pragma unroll
        for (int cg = 0; cg < 4; ++cg)
          oacc[rg][cg] = __builtin_amdgcn_mfma_f32_16x16x32_bf16(pf[rg], vfr[kx][cg],
                                                                 oacc[rg][cg], 0, 0, 0);
        lacc[rg] = __builtin_amdgcn_mfma_f32_16x16x32_bf16(pf[rg], vones,
                                                           lacc[rg], 0, 0, 0);
      }
    }
  }
  // ---- epilogue: broadcast l from ll==0 lanes, divide, store ----
#pragma unroll
  for (int rg = 0; rg < 2; ++rg)
#pragma unroll
    for (int r = 0; r < 4; ++r) {
      float l = __shfl(lacc[rg][r], lane & 48);  // src lane = gl*16 (ll==0)
      float inv = 1.0f / l;
      long i = wq0 + rg * 16 + gl * 4 + r;
#pragma unroll
      for (int cg = 0; cg < 4; ++cg)
        attnb[(bS + i) * 1024 + h * 64 + cg * 16 + ll] = f2b(oacc[rg][cg][r] * inv);
    }
}

extern "C" void kernel_launch(void* const* d_in, const int* in_sizes, int n_in,
                              void* d_out, int out_size, void* d_ws, size_t ws_size,
                              hipStream_t stream) {
  const float* x    = (const float*)d_in[0];
  const float* bias = (const float*)d_in[1];
  const float* Wq   = (const float*)d_in[2];
  const float* Wk   = (const float*)d_in[3];
  const float* Wv   = (const float*)d_in[4];
  const float* Wo   = (const float*)d_in[5];
  float* out = (float*)d_out;

  // workspace layout (39.25 MB total); attnb ALIASES xb (xb dead after GEMM1)
  u16* xb    = (u16*)d_ws;                       // 8192x1024      (16 MB)
  u16* wcat  = xb    + (size_t)8192 * 1024;      // 1152x1024 (N,K) (2.25 MB)
  u16* wot   = wcat  + (size_t)1152 * 1024;      // 1024x1024 (N,K) (2 MB)
  u16* qkvb  = wot   + (size_t)1024 * 1024;      // 8192x1152      (18 MB)
  u16* vtb   = qkvb  + (size_t)8192 * 1152;      // 2x64x4096      (1 MB)
  u16* attnb = xb;                               // reuse xb       (16 MB)

  cast_x_kernel<<<8192, 256, 0, stream>>>(x, xb);
  pack_w_kernel<<<8704, 256, 0, stream>>>(Wq, Wk, Wv, Wo, wcat, wot);
  gemm_bt_kernel<u16><<<dim3(64, 9), 256, 0, stream>>>(xb, wcat, qkvb, 8192, 1152, 1024);
  vt_transpose_kernel<<<128, 256, 0, stream>>>(qkvb, vtb);
  attn_kernel<<<1024, 256, 0, stream>>>(qkvb, vtb, bias, attnb);
  gemm_bt_kernel<float><<<dim3(64, 8), 256, 0, stream>>>(attnb, wot, out, 8192, 1024, 1024);
}

// Round 7
// 220.754 us; speedup vs baseline: 1.1267x; 1.0464x over previous
//
#include <hip/hip_runtime.h>

#define Bx 2
#define Sx 4096
#define Ex 1024
#define Hx 16
#define DHx 64
#define Wwin 512

typedef unsigned short u16;
typedef unsigned int u32;
typedef __attribute__((ext_vector_type(8))) short bf16x8;
typedef __attribute__((ext_vector_type(4))) float f32x4;
typedef __attribute__((ext_vector_type(4))) unsigned short u16x4;

// RTNE float -> bf16 (finite inputs)
__device__ __forceinline__ u16 f2b(float f) {
  unsigned u = __builtin_bit_cast(unsigned, f);
  unsigned r = (u + 0x7FFFu + ((u >> 16) & 1u)) >> 16;
  return (u16)r;
}

// packed f32x2 -> bf16x2 (RTNE), single instruction
__device__ __forceinline__ u32 cvt_pk_bf16(float lo, float hi) {
  u32 r;
  asm("v_cvt_pk_bf16_f32 %0, %1, %2" : "=v"(r) : "v"(lo), "v"(hi));
  return r;
}

// async global->LDS, 16B per lane; LDS dest = wave-uniform base + lane*16
__device__ __forceinline__ void gload_lds16(const void* g, void* l) {
  __builtin_amdgcn_global_load_lds(
      (const __attribute__((address_space(1))) void*)g,
      (__attribute__((address_space(3))) void*)l, 16, 0, 0);
}

// ---------------- cast x (f32 -> bf16), vectorized ----------------
__global__ __launch_bounds__(256) void cast_x_kernel(const float* __restrict__ x,
                                                     u16* __restrict__ xb) {
  long idx = ((long)blockIdx.x * 256 + threadIdx.x) * 4;
  float4 v = *(const float4*)(x + idx);
  u16x4 o;
  o[0] = f2b(v.x); o[1] = f2b(v.y); o[2] = f2b(v.z); o[3] = f2b(v.w);
  *(u16x4*)(xb + idx) = o;
}

// ------------- pack weights: Wcat_t[1152][1024], Wo_t[1024][1024] -------------
__global__ __launch_bounds__(256) void pack_w_kernel(const float* __restrict__ Wq,
                                                     const float* __restrict__ Wk,
                                                     const float* __restrict__ Wv,
                                                     const float* __restrict__ Wo,
                                                     u16* __restrict__ wcat,
                                                     u16* __restrict__ wot) {
  int idx = blockIdx.x * 256 + threadIdx.x;
  if (idx < 1048576) {                       // Wq (E, H*DH)
    int e = idx >> 10, n = idx & 1023;
    wcat[n * 1024 + e] = f2b(Wq[idx]);
  } else if (idx < 1048576 + 65536) {        // Wk (E, 64)
    int i2 = idx - 1048576;
    int e = i2 >> 6, d = i2 & 63;
    wcat[(1024 + d) * 1024 + e] = f2b(Wk[i2]);
  } else if (idx < 1048576 + 131072) {       // Wv (E, 64)
    int i2 = idx - (1048576 + 65536);
    int e = i2 >> 6, d = i2 & 63;
    wcat[(1088 + d) * 1024 + e] = f2b(Wv[i2]);
  } else {                                   // Wo (H*DH, E) -> (E, H*DH)
    int i2 = idx - (1048576 + 131072);
    int hd = i2 >> 10, e = i2 & 1023;
    wot[e * 1024 + hd] = f2b(Wo[i2]);
  }
}

// ---------------- GEMM: C(M,N) = A(M,K) * Bt(N,K)^T, bf16 in, f32 acc ----------------
// 128x128 tile, BK=64; 2-phase double-buffered LDS: stage tile t+1 overlaps
// compute of tile t; ONE __syncthreads per tile (drains vmcnt after compute).
template <typename OutT>
__global__ __launch_bounds__(256) void gemm_bt_kernel(const u16* __restrict__ A,
                                                      const u16* __restrict__ Bt,
                                                      OutT* __restrict__ C,
                                                      int M, int N, int K) {
  __shared__ u16 As[2][128 * 64];
  __shared__ u16 Bs[2][128 * 64];
  const int tid = threadIdx.x;
  const int lane = tid & 63, wave = tid >> 6;
  const int ll = lane & 15, gl = lane >> 4;
  const int wr = wave >> 1, wc = wave & 1;
  const long m0 = (long)blockIdx.x * 128;
  const long n0 = (long)blockIdx.y * 128;
  const int segrow = lane >> 3, cph = lane & 7;

  f32x4 acc[4][4] = {};
  const int nt = K >> 6;

#define GEMM_STAGE(buf, kb)                                                     \
  {                                                                             \
    _Pragma("unroll") for (int q = 0; q < 4; ++q) {                             \
      int s = wave * 4 + q;                                                     \
      int row = s * 8 + segrow;                                                 \
      int clog = cph ^ (row & 7);                                               \
      gload_lds16(A + (m0 + row) * K + (kb) + clog * 8,                         \
                  (char*)&As[buf][0] + s * 1024);                               \
      gload_lds16(Bt + (n0 + row) * K + (kb) + clog * 8,                        \
                  (char*)&Bs[buf][0] + s * 1024);                               \
    }                                                                           \
  }

  GEMM_STAGE(0, 0);
  __syncthreads();
  int cur = 0;
  for (int t = 0; t < nt; ++t) {
    if (t + 1 < nt) GEMM_STAGE(cur ^ 1, (t + 1) * 64);
#pragma unroll
    for (int kx = 0; kx < 2; ++kx) {
      bf16x8 af[4], bfr[4];
#pragma unroll
      for (int rg = 0; rg < 4; ++rg) {
        int row = wr * 64 + rg * 16 + ll;
        int c = kx * 4 + gl;
        af[rg] = *(const bf16x8*)&As[cur][row * 64 + ((c ^ (row & 7)) << 3)];
      }
#pragma unroll
      for (int cg = 0; cg < 4; ++cg) {
        int row = wc * 64 + cg * 16 + ll;
        int c = kx * 4 + gl;
        bfr[cg] = *(const bf16x8*)&Bs[cur][row * 64 + ((c ^ (row & 7)) << 3)];
      }
#pragma unroll
      for (int rg = 0; rg < 4; ++rg)
#pragma unroll
        for (int cg = 0; cg < 4; ++cg)
          acc[rg][cg] = __builtin_amdgcn_mfma_f32_16x16x32_bf16(af[rg], bfr[cg],
                                                                acc[rg][cg], 0, 0, 0);
    }
    __syncthreads();  // drains vmcnt (t+1 staging) + protects WAR for next stage
    cur ^= 1;
  }
#undef GEMM_STAGE
#pragma unroll
  for (int rg = 0; rg < 4; ++rg)
#pragma unroll
    for (int cg = 0; cg < 4; ++cg)
#pragma unroll
      for (int r = 0; r < 4; ++r) {
        long row = m0 + wr * 64 + rg * 16 + gl * 4 + r;
        long col = n0 + wc * 64 + cg * 16 + ll;
        if constexpr (sizeof(OutT) == 2)
          C[row * (long)N + col] = f2b(acc[rg][cg][r]);
        else
          C[row * (long)N + col] = acc[rg][cg][r];
      }
}

// ---------------- V transpose: vt[b][dh=64][S] <- qkvb[.., 1088+dh] ----------------
__global__ __launch_bounds__(256) void vt_transpose_kernel(const u16* __restrict__ qkvb,
                                                           u16* __restrict__ vt) {
  __shared__ u16 T[64 * 65];
  const int blk = blockIdx.x;
  const int b = blk >> 6;
  const int j0 = (blk & 63) * 64;
  const int tid = threadIdx.x;
#pragma unroll
  for (int rep = 0; rep < 16; ++rep) {
    int idx = rep * 256 + tid;
    int jj = idx >> 6, dd = idx & 63;
    T[dd * 65 + jj] = qkvb[((long)b * Sx + j0 + jj) * 1152 + 1088 + dd];
  }
  __syncthreads();
#pragma unroll
  for (int rep = 0; rep < 16; ++rep) {
    int idx = rep * 256 + tid;
    int dd = idx >> 6, jj = idx & 63;
    vt[((long)b * 64 + dd) * Sx + j0 + jj] = T[dd * 65 + jj];
  }
}

// ---------------- sliding-window attention (v3) ----------------
// 4 waves x 32 queries; block-level K/V chunks staged via coalesced
// global_load_lds into DOUBLE-BUFFERED swizzled LDS (2-phase: stage t+1
// overlaps compute t, one barrier per chunk); fixed-M exp2 softmax;
// row-sum l via ones-column MFMA; P via per-wave swizzled LDS.
__global__ __launch_bounds__(256) void attn_kernel(const u16* __restrict__ qkv,
                                                   const u16* __restrict__ vt,
                                                   const float* __restrict__ bias,
                                                   u16* __restrict__ attnb) {
  __shared__ u16 Ks[2][64 * 64];   // [key][dh]  swizzled
  __shared__ u16 Vts[2][64 * 64];  // [dh][key]  swizzled
  __shared__ u16 Pb[4][32 * 64];   // per-wave P, swizzled
  __shared__ float bias2S[512];    // bias*log2e - 24

  // XCD remap: put all 16 heads of a query tile (shared K/V) on one XCD's L2
  const int bid0 = blockIdx.x;
  const int bid = (bid0 & 7) * 128 + (bid0 >> 3);
  const int h = bid & 15;
  const int qt = (bid >> 4) & 31;
  const int b = bid >> 9;
  const int q0 = qt * 128;
  const long bS = (long)b * Sx;

  const int tid = threadIdx.x;
  const int lane = tid & 63, wave = tid >> 6;
  const int ll = lane & 15, gl = lane >> 4;
  const int wq0 = q0 + wave * 32;
  const int segrow = lane >> 3, cph = lane & 7;

  for (int i = tid; i < 512; i += 256)
    bias2S[i] = fmaf(bias[h * 512 + i], 1.4426950408889634f, -24.0f);

  const float C1 = 0.125f * 1.4426950408889634f;  // scale * log2e

  bf16x8 qf[2][2];  // [q rowgroup][k-step]
#pragma unroll
  for (int rg = 0; rg < 2; ++rg)
#pragma unroll
    for (int kx = 0; kx < 2; ++kx)
      qf[rg][kx] = *(const bf16x8*)&qkv[(bS + wq0 + rg * 16 + ll) * 1152 +
                                        h * 64 + kx * 32 + gl * 8];

  // ones-column fragment for l (V^T row 64 == 1, rows 65..79 == 0)
  u16 ov = (ll == 0) ? (u16)0x3F80 : (u16)0;
  bf16x8 vones;
#pragma unroll
  for (int i = 0; i < 8; ++i) vones[i] = (short)ov;

  f32x4 oacc[2][4] = {};
  f32x4 lacc[2] = {};

  u16* Pw = &Pb[wave][0];

#define ATTN_STAGE(buf, kb)                                                     \
  {                                                                             \
    _Pragma("unroll") for (int q = 0; q < 2; ++q) {                             \
      int s = wave * 2 + q;                                                     \
      int rrow = s * 8 + segrow; /* key for Ks, dh for Vts */                   \
      int clog = cph ^ (rrow & 7);                                              \
      gload_lds16(qkv + (bS + (kb) + rrow) * 1152 + 1024 + clog * 8,            \
                  (char*)&Ks[buf][0] + s * 1024);                               \
      gload_lds16(vt + ((long)b * 64 + rrow) * Sx + (kb) + clog * 8,            \
                  (char*)&Vts[buf][0] + s * 1024);                              \
    }                                                                           \
  }

  // block-level chunk range: keys [q0-512, q0+128)
  const int kb_start = (q0 > 511) ? (q0 - 512) : 0;
  const int kb_end = q0 + 64;  // inclusive
  ATTN_STAGE(0, kb_start);
  __syncthreads();  // drains prologue staging; also covers bias2S
  int cur = 0;
  for (int kb = kb_start; kb <= kb_end; kb += 64) {
    if (kb + 64 <= kb_end) ATTN_STAGE(cur ^ 1, kb + 64);
    const bool active = (kb <= wq0 + 31) && (kb + 63 >= wq0 - 511);
    if (active) {
      // S = Q K^T  (rows=q, cols=key)
      f32x4 sacc[2][4] = {};
#pragma unroll
      for (int kx = 0; kx < 2; ++kx) {
        bf16x8 kf[4];
#pragma unroll
        for (int cg = 0; cg < 4; ++cg) {
          int key = cg * 16 + ll;
          int c = kx * 4 + gl;
          kf[cg] = *(const bf16x8*)&Ks[cur][key * 64 + ((c ^ (key & 7)) << 3)];
        }
#pragma unroll
        for (int rg = 0; rg < 2; ++rg)
#pragma unroll
          for (int cg = 0; cg < 4; ++cg)
            sacc[rg][cg] = __builtin_amdgcn_mfma_f32_16x16x32_bf16(qf[rg][kx], kf[cg],
                                                                   sacc[rg][cg], 0, 0, 0);
      }
      // fixed-M softmax: p = exp2(qk*C1 + bias2[d])
      const int dbase = (wq0 - kb) + gl * 4 - ll;  // d = dbase + rg*16 + r - cg*16
      const bool full = (kb - wq0 >= -480) && (kb - wq0 <= -64);
      if (full) {
        const float* bp = bias2S + dbase;
#pragma unroll
        for (int rg = 0; rg < 2; ++rg)
#pragma unroll
          for (int cg = 0; cg < 4; ++cg)
#pragma unroll
            for (int r = 0; r < 4; ++r)
              sacc[rg][cg][r] =
                  __builtin_exp2f(fmaf(sacc[rg][cg][r], C1, bp[rg * 16 + r - cg * 16]));
      } else {
#pragma unroll
        for (int rg = 0; rg < 2; ++rg)
#pragma unroll
          for (int cg = 0; cg < 4; ++cg)
#pragma unroll
            for (int r = 0; r < 4; ++r) {
              int d = dbase + rg * 16 + r - cg * 16;
              int dc = d < 0 ? 0 : (d > 511 ? 511 : d);
              float p = __builtin_exp2f(fmaf(sacc[rg][cg][r], C1, bias2S[dc]));
              sacc[rg][cg][r] = ((unsigned)d < 512u) ? p : 0.0f;
            }
      }
      // P -> per-wave LDS (bf16, swizzled), packed converts
#pragma unroll
      for (int rg = 0; rg < 2; ++rg)
#pragma unroll
        for (int cg = 0; cg < 4; ++cg)
#pragma unroll
          for (int rp = 0; rp < 2; ++rp) {
            u32 pk = cvt_pk_bf16(sacc[rg][cg][2 * rp], sacc[rg][cg][2 * rp + 1]);
            int row0 = rg * 16 + gl * 4 + 2 * rp;
            int col = cg * 16 + ll;
            Pw[row0 * 64 + (((col >> 3) ^ (row0 & 7)) << 3) + (col & 7)] = (u16)pk;
            int row1 = row0 + 1;
            Pw[row1 * 64 + (((col >> 3) ^ (row1 & 7)) << 3) + (col & 7)] =
                (u16)(pk >> 16);
          }
      // O += P V ; l += P * 1
#pragma unroll
      for (int kx = 0; kx < 2; ++kx) {
        bf16x8 pf[2], vf[4];
#pragma unroll
        for (int rg = 0; rg < 2; ++rg) {
          int row = rg * 16 + ll;
          int c = kx * 4 + gl;
          pf[rg] = *(const bf16x8*)&Pw[row * 64 + ((c ^ (row & 7)) << 3)];
        }
#pragma unroll
        for (int cg = 0; cg < 4; ++cg) {
          int dh = cg * 16 + ll;
          int c = kx * 4 + gl;
          vf[cg] = *(const bf16x8*)&Vts[cur][dh * 64 + ((c ^ (dh & 7)) << 3)];
        }
#pragma unroll
        for (int rg = 0; rg < 2; ++rg) {
#pragma unroll
          for (int cg = 0; cg < 4; ++cg)
            oacc[rg][cg] = __builtin_amdgcn_mfma_f32_16x16x32_bf16(pf[rg], vf[cg],
                                                                   oacc[rg][cg], 0, 0, 0);
          lacc[rg] = __builtin_amdgcn_mfma_f32_16x16x32_bf16(pf[rg], vones,
                                                             lacc[rg], 0, 0, 0);
        }
      }
    }
    __syncthreads();  // drains next-chunk staging; protects buffers (WAR)
    cur ^= 1;
  }
#undef ATTN_STAGE
  // epilogue: broadcast l from ll==0 lanes, divide, store
#pragma unroll
  for (int rg = 0; rg < 2; ++rg)
#pragma unroll
    for (int r = 0; r < 4; ++r) {
      float l = __shfl(lacc[rg][r], lane & 48);  // src lane = gl*16 (ll==0)
      float inv = 1.0f / l;
      long i = wq0 + rg * 16 + gl * 4 + r;
#pragma unroll
      for (int cg = 0; cg < 4; ++cg)
        attnb[(bS + i) * 1024 + h * 64 + cg * 16 + ll] = f2b(oacc[rg][cg][r] * inv);
    }
}

extern "C" void kernel_launch(void* const* d_in, const int* in_sizes, int n_in,
                              void* d_out, int out_size, void* d_ws, size_t ws_size,
                              hipStream_t stream) {
  const float* x    = (const float*)d_in[0];
  const float* bias = (const float*)d_in[1];
  const float* Wq   = (const float*)d_in[2];
  const float* Wk   = (const float*)d_in[3];
  const float* Wv   = (const float*)d_in[4];
  const float* Wo   = (const float*)d_in[5];
  float* out = (float*)d_out;

  // workspace layout (39.25 MB total); attnb ALIASES xb (xb dead after GEMM1)
  u16* xb    = (u16*)d_ws;                       // 8192x1024      (16 MB)
  u16* wcat  = xb    + (size_t)8192 * 1024;      // 1152x1024 (N,K) (2.25 MB)
  u16* wot   = wcat  + (size_t)1152 * 1024;      // 1024x1024 (N,K) (2 MB)
  u16* qkvb  = wot   + (size_t)1024 * 1024;      // 8192x1152      (18 MB)
  u16* vtb   = qkvb  + (size_t)8192 * 1152;      // 2x64x4096      (1 MB)
  u16* attnb = xb;                               // reuse xb       (16 MB)

  cast_x_kernel<<<8192, 256, 0, stream>>>(x, xb);
  pack_w_kernel<<<8704, 256, 0, stream>>>(Wq, Wk, Wv, Wo, wcat, wot);
  gemm_bt_kernel<u16><<<dim3(64, 9), 256, 0, stream>>>(xb, wcat, qkvb, 8192, 1152, 1024);
  vt_transpose_kernel<<<128, 256, 0, stream>>>(qkvb, vtb);
  attn_kernel<<<1024, 256, 0, stream>>>(qkvb, vtb, bias, attnb);
  gemm_bt_kernel<float><<<dim3(64, 8), 256, 0, stream>>>(attnb, wot, out, 8192, 1024, 1024);
}

// Round 8
// 208.942 us; speedup vs baseline: 1.1904x; 1.0565x over previous
//
#include <hip/hip_runtime.h>

#define Bx 2
#define Sx 4096
#define Ex 1024
#define Hx 16
#define DHx 64
#define Wwin 512

typedef unsigned short u16;
typedef unsigned int u32;
typedef __attribute__((ext_vector_type(8))) short bf16x8;
typedef __attribute__((ext_vector_type(4))) float f32x4;
typedef __attribute__((ext_vector_type(16))) float f32x16;
typedef __attribute__((ext_vector_type(4))) int i32x4;
typedef __attribute__((ext_vector_type(4))) unsigned short u16x4;

// RTNE float -> bf16 (finite inputs)
__device__ __forceinline__ u16 f2b(float f) {
  unsigned u = __builtin_bit_cast(unsigned, f);
  unsigned r = (u + 0x7FFFu + ((u >> 16) & 1u)) >> 16;
  return (u16)r;
}

// packed f32x2 -> bf16x2 (RTNE), single instruction
__device__ __forceinline__ u32 cvt_pk_bf16(float lo, float hi) {
  u32 r;
  asm("v_cvt_pk_bf16_f32 %0, %1, %2" : "=v"(r) : "v"(lo), "v"(hi));
  return r;
}

// async global->LDS, 16B per lane; LDS dest = wave-uniform base + lane*16
__device__ __forceinline__ void gload_lds16(const void* g, void* l) {
  __builtin_amdgcn_global_load_lds(
      (const __attribute__((address_space(1))) void*)g,
      (__attribute__((address_space(3))) void*)l, 16, 0, 0);
}

// ---------------- cast x (f32 -> bf16), vectorized ----------------
__global__ __launch_bounds__(256) void cast_x_kernel(const float* __restrict__ x,
                                                     u16* __restrict__ xb) {
  long idx = ((long)blockIdx.x * 256 + threadIdx.x) * 4;
  float4 v = *(const float4*)(x + idx);
  u16x4 o;
  o[0] = f2b(v.x); o[1] = f2b(v.y); o[2] = f2b(v.z); o[3] = f2b(v.w);
  *(u16x4*)(xb + idx) = o;
}

// ------------- pack weights: Wcat_t[1152][1024], Wo_t[1024][1024] -------------
__global__ __launch_bounds__(256) void pack_w_kernel(const float* __restrict__ Wq,
                                                     const float* __restrict__ Wk,
                                                     const float* __restrict__ Wv,
                                                     const float* __restrict__ Wo,
                                                     u16* __restrict__ wcat,
                                                     u16* __restrict__ wot) {
  int idx = blockIdx.x * 256 + threadIdx.x;
  if (idx < 1048576) {                       // Wq (E, H*DH)
    int e = idx >> 10, n = idx & 1023;
    wcat[n * 1024 + e] = f2b(Wq[idx]);
  } else if (idx < 1048576 + 65536) {        // Wk (E, 64)
    int i2 = idx - 1048576;
    int e = i2 >> 6, d = i2 & 63;
    wcat[(1024 + d) * 1024 + e] = f2b(Wk[i2]);
  } else if (idx < 1048576 + 131072) {       // Wv (E, 64)
    int i2 = idx - (1048576 + 65536);
    int e = i2 >> 6, d = i2 & 63;
    wcat[(1088 + d) * 1024 + e] = f2b(Wv[i2]);
  } else {                                   // Wo (H*DH, E) -> (E, H*DH)
    int i2 = idx - (1048576 + 131072);
    int hd = i2 >> 10, e = i2 & 1023;
    wot[e * 1024 + hd] = f2b(Wo[i2]);
  }
}

// ---------------- GEMM: C(M,N) = A(M,K) * Bt(N,K)^T, bf16 in, f32 acc ----------------
// Round-2 single-buffer version (reverted: 2-phase dbuf cost a block/CU, m132 lesson).
template <typename OutT>
__global__ __launch_bounds__(256) void gemm_bt_kernel(const u16* __restrict__ A,
                                                      const u16* __restrict__ Bt,
                                                      OutT* __restrict__ C,
                                                      int M, int N, int K) {
  __shared__ u16 As[128 * 64];
  __shared__ u16 Bs[128 * 64];
  const int tid = threadIdx.x;
  const int lane = tid & 63, wave = tid >> 6;
  const int ll = lane & 15, gl = lane >> 4;
  const int wr = wave >> 1, wc = wave & 1;
  const long m0 = (long)blockIdx.x * 128;
  const long n0 = (long)blockIdx.y * 128;
  const int segrow = lane >> 3, cph = lane & 7;

  f32x4 acc[4][4] = {};

  for (int kb = 0; kb < K; kb += 64) {
    __syncthreads();
#pragma unroll
    for (int q = 0; q < 4; ++q) {
      int s = wave * 4 + q;
      int row = s * 8 + segrow;
      int clog = cph ^ (row & 7);
      gload_lds16(A + (m0 + row) * K + kb + clog * 8, (char*)As + s * 1024);
      gload_lds16(Bt + (n0 + row) * K + kb + clog * 8, (char*)Bs + s * 1024);
    }
    __syncthreads();
#pragma unroll
    for (int kx = 0; kx < 2; ++kx) {
      bf16x8 af[4], bfr[4];
#pragma unroll
      for (int rg = 0; rg < 4; ++rg) {
        int row = wr * 64 + rg * 16 + ll;
        int c = kx * 4 + gl;
        af[rg] = *(const bf16x8*)&As[row * 64 + ((c ^ (row & 7)) << 3)];
      }
#pragma unroll
      for (int cg = 0; cg < 4; ++cg) {
        int row = wc * 64 + cg * 16 + ll;
        int c = kx * 4 + gl;
        bfr[cg] = *(const bf16x8*)&Bs[row * 64 + ((c ^ (row & 7)) << 3)];
      }
#pragma unroll
      for (int rg = 0; rg < 4; ++rg)
#pragma unroll
        for (int cg = 0; cg < 4; ++cg)
          acc[rg][cg] = __builtin_amdgcn_mfma_f32_16x16x32_bf16(af[rg], bfr[cg],
                                                                acc[rg][cg], 0, 0, 0);
    }
  }
#pragma unroll
  for (int rg = 0; rg < 4; ++rg)
#pragma unroll
    for (int cg = 0; cg < 4; ++cg)
#pragma unroll
      for (int r = 0; r < 4; ++r) {
        long row = m0 + wr * 64 + rg * 16 + gl * 4 + r;
        long col = n0 + wc * 64 + cg * 16 + ll;
        if constexpr (sizeof(OutT) == 2)
          C[row * (long)N + col] = f2b(acc[rg][cg][r]);
        else
          C[row * (long)N + col] = acc[rg][cg][r];
      }
}

// ---------------- V transpose: vt[b][dh=64][S] <- qkvb[.., 1088+dh] ----------------
__global__ __launch_bounds__(256) void vt_transpose_kernel(const u16* __restrict__ qkvb,
                                                           u16* __restrict__ vt) {
  __shared__ u16 T[64 * 65];
  const int blk = blockIdx.x;
  const int b = blk >> 6;
  const int j0 = (blk & 63) * 64;
  const int tid = threadIdx.x;
#pragma unroll
  for (int rep = 0; rep < 16; ++rep) {
    int idx = rep * 256 + tid;
    int jj = idx >> 6, dd = idx & 63;
    T[dd * 65 + jj] = qkvb[((long)b * Sx + j0 + jj) * 1152 + 1088 + dd];
  }
  __syncthreads();
#pragma unroll
  for (int rep = 0; rep < 16; ++rep) {
    int idx = rep * 256 + tid;
    int dd = idx >> 6, jj = idx & 63;
    vt[((long)b * 64 + dd) * Sx + j0 + jj] = T[dd * 65 + jj];
  }
}

// ---------------- sliding-window attention (v4: 32x32 swapped QK, in-reg P) ------
// 4 waves x 32 queries; 2-phase double-buffered K/V staging; swapped QK^T
// (mfma(K,Q)) so each lane holds P[16 keys][q=lane&31]; P->PV A-frag built
// in-register via cvt_pk + v_permlane32_swap (NO P-LDS roundtrip); fixed-M
// exp2 softmax; l via all-ones-B MFMA (row layout matches oacc exactly).
__global__ __launch_bounds__(256) void attn_kernel(const u16* __restrict__ qkv,
                                                   const u16* __restrict__ vt,
                                                   const float* __restrict__ bias,
                                                   u16* __restrict__ attnb) {
  __shared__ u16 Ks[2][64 * 64];   // [key][dh]  swizzled 16B chunks: c^(key&7)
  __shared__ u16 Vts[2][64 * 64];  // [dh][key]  swizzled
  __shared__ float bias2S[512];    // bias*log2e - 24

  // XCD remap: all 16 heads of a query tile (shared K/V) on one XCD's L2
  const int bid0 = blockIdx.x;
  const int bid = (bid0 & 7) * 128 + (bid0 >> 3);
  const int h = bid & 15;
  const int qt = (bid >> 4) & 31;
  const int b = bid >> 9;
  const int q0 = qt * 128;
  const long bS = (long)b * Sx;

  const int tid = threadIdx.x;
  const int lane = tid & 63, wave = tid >> 6;
  const int ql = lane & 31;   // q within wave tile (m/n index)
  const int hi = lane >> 5;   // k-half for 32x32 fragments
  const int wq0 = q0 + wave * 32;
  const int segrow = lane >> 3, cph = lane & 7;

  for (int i = tid; i < 512; i += 256)
    bias2S[i] = fmaf(bias[h * 512 + i], 1.4426950408889634f, -24.0f);

  const float C1 = 0.125f * 1.4426950408889634f;  // scale * log2e

  // Q as B-frags: lane&31 = q, k = dh = s*16 + hi*8 + {0..7}
  bf16x8 qf[4];
#pragma unroll
  for (int s = 0; s < 4; ++s)
    qf[s] = *(const bf16x8*)&qkv[(bS + wq0 + ql) * 1152 + h * 64 + s * 16 + hi * 8];

  bf16x8 vones;  // all-ones B-frag: D[q][*] = row-sum l[q] in every column
#pragma unroll
  for (int i = 0; i < 8; ++i) vones[i] = (short)0x3F80;

  f32x16 oacc[2] = {};  // [dhblk]: D row q=(r&3)+8*(r>>2)+4*hi, col dh=dhblk*32+ql
  f32x16 lacc = {};     // same row layout as oacc

#define ATTN_STAGE(buf, kb)                                                     \
  {                                                                             \
    _Pragma("unroll") for (int q = 0; q < 2; ++q) {                             \
      int s = wave * 2 + q;                                                     \
      int rrow = s * 8 + segrow; /* key for Ks, dh for Vts */                   \
      int clog = cph ^ (rrow & 7);                                              \
      gload_lds16(qkv + (bS + (kb) + rrow) * 1152 + 1024 + clog * 8,            \
                  (char*)&Ks[buf][0] + s * 1024);                               \
      gload_lds16(vt + ((long)b * 64 + rrow) * Sx + (kb) + clog * 8,            \
                  (char*)&Vts[buf][0] + s * 1024);                              \
    }                                                                           \
  }

  const int kb_start = (q0 > 511) ? (q0 - 512) : 0;
  const int kb_end = q0 + 64;  // inclusive
  ATTN_STAGE(0, kb_start);
  __syncthreads();  // drains prologue staging; also covers bias2S
  int cur = 0;
  for (int kb = kb_start; kb <= kb_end; kb += 64) {
    if (kb + 64 <= kb_end) ATTN_STAGE(cur ^ 1, kb + 64);
    const bool active = (kb <= wq0 + 31) && (kb + 63 >= wq0 - 511);
    if (active) {
      // S[key][q]: sacc[kblk] reg r -> key = kblk*32+(r&3)+8*(r>>2)+4*hi, q = ql
      f32x16 sacc[2] = {};
#pragma unroll
      for (int kblk = 0; kblk < 2; ++kblk) {
        int key = kblk * 32 + ql;
#pragma unroll
        for (int s = 0; s < 4; ++s) {
          int c = 2 * s + hi;
          bf16x8 kf = *(const bf16x8*)&Ks[cur][key * 64 + ((c ^ (key & 7)) << 3)];
          sacc[kblk] = __builtin_amdgcn_mfma_f32_32x32x16_bf16(kf, qf[s],
                                                               sacc[kblk], 0, 0, 0);
        }
      }
      // fixed-M softmax: p = exp2(qk*C1 + bias2[d]), d = q - j
      const int dbase = wq0 + ql - kb - 4 * hi;
      const bool full = (kb - wq0 >= -480) && (kb - wq0 <= -64);
      if (full) {
        const float* bpz = bias2S + dbase - 63;  // idx 63-off >= 0 folds as imm
#pragma unroll
        for (int kblk = 0; kblk < 2; ++kblk)
#pragma unroll
          for (int r = 0; r < 16; ++r) {
            const int off = kblk * 32 + (r & 3) + 8 * (r >> 2);
            sacc[kblk][r] = __builtin_exp2f(fmaf(sacc[kblk][r], C1, bpz[63 - off]));
          }
      } else {
#pragma unroll
        for (int kblk = 0; kblk < 2; ++kblk)
#pragma unroll
          for (int r = 0; r < 16; ++r) {
            const int off = kblk * 32 + (r & 3) + 8 * (r >> 2);
            int d = dbase - off;
            int dc = d < 0 ? 0 : (d > 511 ? 511 : d);
            float p = __builtin_exp2f(fmaf(sacc[kblk][r], C1, bias2S[dc]));
            sacc[kblk][r] = ((unsigned)d < 512u) ? p : 0.0f;
          }
      }
      // PV: per K-16 step, build A-frag in-register (cvt_pk + permlane32_swap)
#pragma unroll
      for (int s = 0; s < 4; ++s) {
        const int kblk = s >> 1;
        const int m0 = 2 * (s & 1);  // this lane's low reg-group for step s
        u32 a0 = cvt_pk_bf16(sacc[kblk][4 * m0 + 0], sacc[kblk][4 * m0 + 1]);
        u32 a1 = cvt_pk_bf16(sacc[kblk][4 * m0 + 2], sacc[kblk][4 * m0 + 3]);
        u32 b0 = cvt_pk_bf16(sacc[kblk][4 * m0 + 4], sacc[kblk][4 * m0 + 5]);
        u32 b1 = cvt_pk_bf16(sacc[kblk][4 * m0 + 6], sacc[kblk][4 * m0 + 7]);
        // (w0,w2) = swap(a0,b0): hi-half of dst <-> lo-half of src
        asm("v_permlane32_swap_b32 %0, %1" : "+v"(a0), "+v"(b0));
        asm("v_permlane32_swap_b32 %0, %1" : "+v"(a1), "+v"(b1));
        i32x4 t;
        t.x = (int)a0; t.y = (int)a1; t.z = (int)b0; t.w = (int)b1;
        bf16x8 pa = __builtin_bit_cast(bf16x8, t);
        lacc = __builtin_amdgcn_mfma_f32_32x32x16_bf16(pa, vones, lacc, 0, 0, 0);
#pragma unroll
        for (int dhblk = 0; dhblk < 2; ++dhblk) {
          int dh = dhblk * 32 + ql;
          int c = 2 * s + hi;
          bf16x8 vf = *(const bf16x8*)&Vts[cur][dh * 64 + ((c ^ (dh & 7)) << 3)];
          oacc[dhblk] = __builtin_amdgcn_mfma_f32_32x32x16_bf16(pa, vf,
                                                                oacc[dhblk], 0, 0, 0);
        }
      }
    }
    __syncthreads();  // drains next-chunk staging; protects buffers (WAR)
    cur ^= 1;
  }
#undef ATTN_STAGE
  // epilogue: out = O / l ; lacc rows match oacc rows exactly (no shuffle)
#pragma unroll
  for (int r = 0; r < 16; ++r) {
    const int q = (r & 3) + 8 * (r >> 2) + 4 * hi;
    float inv = 1.0f / lacc[r];
    long row = (bS + wq0 + q) * 1024 + h * 64;
#pragma unroll
    for (int dhblk = 0; dhblk < 2; ++dhblk)
      attnb[row + dhblk * 32 + ql] = f2b(oacc[dhblk][r] * inv);
  }
}

extern "C" void kernel_launch(void* const* d_in, const int* in_sizes, int n_in,
                              void* d_out, int out_size, void* d_ws, size_t ws_size,
                              hipStream_t stream) {
  const float* x    = (const float*)d_in[0];
  const float* bias = (const float*)d_in[1];
  const float* Wq   = (const float*)d_in[2];
  const float* Wk   = (const float*)d_in[3];
  const float* Wv   = (const float*)d_in[4];
  const float* Wo   = (const float*)d_in[5];
  float* out = (float*)d_out;

  // workspace layout (39.25 MB total); attnb ALIASES xb (xb dead after GEMM1)
  u16* xb    = (u16*)d_ws;                       // 8192x1024      (16 MB)
  u16* wcat  = xb    + (size_t)8192 * 1024;      // 1152x1024 (N,K) (2.25 MB)
  u16* wot   = wcat  + (size_t)1152 * 1024;      // 1024x1024 (N,K) (2 MB)
  u16* qkvb  = wot   + (size_t)1024 * 1024;      // 8192x1152      (18 MB)
  u16* vtb   = qkvb  + (size_t)8192 * 1152;      // 2x64x4096      (1 MB)
  u16* attnb = xb;                               // reuse xb       (16 MB)

  cast_x_kernel<<<8192, 256, 0, stream>>>(x, xb);
  pack_w_kernel<<<8704, 256, 0, stream>>>(Wq, Wk, Wv, Wo, wcat, wot);
  gemm_bt_kernel<u16><<<dim3(64, 9), 256, 0, stream>>>(xb, wcat, qkvb, 8192, 1152, 1024);
  vt_transpose_kernel<<<128, 256, 0, stream>>>(qkvb, vtb);
  attn_kernel<<<1024, 256, 0, stream>>>(qkvb, vtb, bias, attnb);
  gemm_bt_kernel<float><<<dim3(64, 8), 256, 0, stream>>>(attnb, wot, out, 8192, 1024, 1024);
}

// Round 9
// 206.509 us; speedup vs baseline: 1.2045x; 1.0118x over previous
//
#include <hip/hip_runtime.h>

#define Bx 2
#define Sx 4096
#define Ex 1024
#define Hx 16
#define DHx 64
#define Wwin 512

typedef unsigned short u16;
typedef unsigned int u32;
typedef __attribute__((ext_vector_type(8))) short bf16x8;
typedef __attribute__((ext_vector_type(4))) float f32x4;
typedef __attribute__((ext_vector_type(16))) float f32x16;
typedef __attribute__((ext_vector_type(4))) int i32x4;
typedef __attribute__((ext_vector_type(4))) unsigned short u16x4;

// RTNE float -> bf16 (finite inputs)
__device__ __forceinline__ u16 f2b(float f) {
  unsigned u = __builtin_bit_cast(unsigned, f);
  unsigned r = (u + 0x7FFFu + ((u >> 16) & 1u)) >> 16;
  return (u16)r;
}

// packed f32x2 -> bf16x2 (RTNE), single instruction
__device__ __forceinline__ u32 cvt_pk_bf16(float lo, float hi) {
  u32 r;
  asm("v_cvt_pk_bf16_f32 %0, %1, %2" : "=v"(r) : "v"(lo), "v"(hi));
  return r;
}

// async global->LDS, 16B per lane; LDS dest = wave-uniform base + lane*16
__device__ __forceinline__ void gload_lds16(const void* g, void* l) {
  __builtin_amdgcn_global_load_lds(
      (const __attribute__((address_space(1))) void*)g,
      (__attribute__((address_space(3))) void*)l, 16, 0, 0);
}

// ---------------- cast x (f32 -> bf16), vectorized ----------------
__global__ __launch_bounds__(256) void cast_x_kernel(const float* __restrict__ x,
                                                     u16* __restrict__ xb) {
  long idx = ((long)blockIdx.x * 256 + threadIdx.x) * 4;
  float4 v = *(const float4*)(x + idx);
  u16x4 o;
  o[0] = f2b(v.x); o[1] = f2b(v.y); o[2] = f2b(v.z); o[3] = f2b(v.w);
  *(u16x4*)(xb + idx) = o;
}

// ------------- pack weights via LDS-tiled 64x64 transpose (coalesced R+W) -----
// wcat[n][e] (n<1024:Wq, 1024..1087:Wk, 1088..1151:Wv); wot[e][hd] = Wo[hd][e]
__global__ __launch_bounds__(256) void pack_w_kernel(const float* __restrict__ Wq,
                                                     const float* __restrict__ Wk,
                                                     const float* __restrict__ Wv,
                                                     const float* __restrict__ Wo,
                                                     u16* __restrict__ wcat,
                                                     u16* __restrict__ wot) {
  __shared__ u16 T[64][65];
  const int blk = blockIdx.x;
  const float* S; u16* D; int Cld, r0, c0;
  if (blk < 256)      { S = Wq; D = wcat;               Cld = 1024; r0 = (blk >> 4) * 64;        c0 = (blk & 15) * 64; }
  else if (blk < 272) { S = Wk; D = wcat + 1024 * 1024; Cld = 64;   r0 = (blk - 256) * 64;       c0 = 0; }
  else if (blk < 288) { S = Wv; D = wcat + 1088 * 1024; Cld = 64;   r0 = (blk - 272) * 64;       c0 = 0; }
  else                { S = Wo; D = wot;                Cld = 1024; r0 = ((blk - 288) >> 4) * 64; c0 = ((blk - 288) & 15) * 64; }
  const int t = threadIdx.x;
  const int tr = t >> 4, tc = (t & 15) * 4;
#pragma unroll
  for (int p = 0; p < 4; ++p) {
    int r = p * 16 + tr;
    float4 v = *(const float4*)&S[(long)(r0 + r) * Cld + c0 + tc];
    T[tc + 0][r] = f2b(v.x); T[tc + 1][r] = f2b(v.y);
    T[tc + 2][r] = f2b(v.z); T[tc + 3][r] = f2b(v.w);
  }
  __syncthreads();
#pragma unroll
  for (int p = 0; p < 4; ++p) {
    int c = p * 16 + tr;
    u16x4 o;
    o[0] = T[c][tc]; o[1] = T[c][tc + 1]; o[2] = T[c][tc + 2]; o[3] = T[c][tc + 3];
    *(u16x4*)&D[(long)(c0 + c) * 1024 + r0 + tc] = o;
  }
}

// ---------------- GEMM: C(M,N) = A(M,K) * Bt(N,K)^T, bf16 in, f32 acc ----------------
// Round-2 single-buffer version (known-good; 2-phase dbuf cost a block/CU).
template <typename OutT>
__global__ __launch_bounds__(256) void gemm_bt_kernel(const u16* __restrict__ A,
                                                      const u16* __restrict__ Bt,
                                                      OutT* __restrict__ C,
                                                      int M, int N, int K) {
  __shared__ u16 As[128 * 64];
  __shared__ u16 Bs[128 * 64];
  const int tid = threadIdx.x;
  const int lane = tid & 63, wave = tid >> 6;
  const int ll = lane & 15, gl = lane >> 4;
  const int wr = wave >> 1, wc = wave & 1;
  const long m0 = (long)blockIdx.x * 128;
  const long n0 = (long)blockIdx.y * 128;
  const int segrow = lane >> 3, cph = lane & 7;

  f32x4 acc[4][4] = {};

  for (int kb = 0; kb < K; kb += 64) {
    __syncthreads();
#pragma unroll
    for (int q = 0; q < 4; ++q) {
      int s = wave * 4 + q;
      int row = s * 8 + segrow;
      int clog = cph ^ (row & 7);
      gload_lds16(A + (m0 + row) * K + kb + clog * 8, (char*)As + s * 1024);
      gload_lds16(Bt + (n0 + row) * K + kb + clog * 8, (char*)Bs + s * 1024);
    }
    __syncthreads();
#pragma unroll
    for (int kx = 0; kx < 2; ++kx) {
      bf16x8 af[4], bfr[4];
#pragma unroll
      for (int rg = 0; rg < 4; ++rg) {
        int row = wr * 64 + rg * 16 + ll;
        int c = kx * 4 + gl;
        af[rg] = *(const bf16x8*)&As[row * 64 + ((c ^ (row & 7)) << 3)];
      }
#pragma unroll
      for (int cg = 0; cg < 4; ++cg) {
        int row = wc * 64 + cg * 16 + ll;
        int c = kx * 4 + gl;
        bfr[cg] = *(const bf16x8*)&Bs[row * 64 + ((c ^ (row & 7)) << 3)];
      }
#pragma unroll
      for (int rg = 0; rg < 4; ++rg)
#pragma unroll
        for (int cg = 0; cg < 4; ++cg)
          acc[rg][cg] = __builtin_amdgcn_mfma_f32_16x16x32_bf16(af[rg], bfr[cg],
                                                                acc[rg][cg], 0, 0, 0);
    }
  }
#pragma unroll
  for (int rg = 0; rg < 4; ++rg)
#pragma unroll
    for (int cg = 0; cg < 4; ++cg)
#pragma unroll
      for (int r = 0; r < 4; ++r) {
        long row = m0 + wr * 64 + rg * 16 + gl * 4 + r;
        long col = n0 + wc * 64 + cg * 16 + ll;
        if constexpr (sizeof(OutT) == 2)
          C[row * (long)N + col] = f2b(acc[rg][cg][r]);
        else
          C[row * (long)N + col] = acc[rg][cg][r];
      }
}

// ---------------- V transpose: vt[b][dh=64][S] <- qkvb[.., 1088+dh] ----------------
__global__ __launch_bounds__(256) void vt_transpose_kernel(const u16* __restrict__ qkvb,
                                                           u16* __restrict__ vt) {
  __shared__ u16 T[64 * 65];
  const int blk = blockIdx.x;
  const int b = blk >> 6;
  const int j0 = (blk & 63) * 64;
  const int tid = threadIdx.x;
#pragma unroll
  for (int rep = 0; rep < 16; ++rep) {
    int idx = rep * 256 + tid;
    int jj = idx >> 6, dd = idx & 63;
    T[dd * 65 + jj] = qkvb[((long)b * Sx + j0 + jj) * 1152 + 1088 + dd];
  }
  __syncthreads();
#pragma unroll
  for (int rep = 0; rep < 16; ++rep) {
    int idx = rep * 256 + tid;
    int dd = idx >> 6, jj = idx & 63;
    vt[((long)b * 64 + dd) * Sx + j0 + jj] = T[dd * 65 + jj];
  }
}

// ---------------- sliding-window attention (v5: 8 waves, QBLK=256) ----------------
// 8 waves x 32 queries (QBLK=256); K/V chunk staged ONCE per block for all 8
// waves (stage+barrier amortized 2x vs v4); 2-phase double-buffer; swapped
// 32x32 QK^T; in-register P via cvt_pk + permlane32_swap; fixed-M exp2
// softmax; l via all-ones-B MFMA.
__global__ __launch_bounds__(512) void attn_kernel(const u16* __restrict__ qkv,
                                                   const u16* __restrict__ vt,
                                                   const float* __restrict__ bias,
                                                   u16* __restrict__ attnb) {
  __shared__ u16 Ks[2][64 * 64];   // [key][dh]  swizzled 16B chunks: c^(key&7)
  __shared__ u16 Vts[2][64 * 64];  // [dh][key]  swizzled
  __shared__ float bias2S[512];    // bias*log2e - 24

  // XCD remap (512 blocks, bijective)
  const int bid0 = blockIdx.x;
  const int bid = (bid0 & 7) * 64 + (bid0 >> 3);
  const int h = bid & 15;
  const int qt = (bid >> 4) & 15;
  const int b = bid >> 8;
  const int q0 = qt * 256;
  const long bS = (long)b * Sx;

  const int tid = threadIdx.x;
  const int lane = tid & 63, wave = tid >> 6;   // 8 waves
  const int ql = lane & 31;   // q within wave tile (m/n index)
  const int hi = lane >> 5;   // k-half for 32x32 fragments
  const int wq0 = q0 + wave * 32;
  const int segrow = lane >> 3, cph = lane & 7;

  if (tid < 512)
    bias2S[tid] = fmaf(bias[h * 512 + tid], 1.4426950408889634f, -24.0f);

  const float C1 = 0.125f * 1.4426950408889634f;  // scale * log2e

  // Q as B-frags: lane&31 = q, k = dh = s*16 + hi*8 + {0..7}
  bf16x8 qf[4];
#pragma unroll
  for (int s = 0; s < 4; ++s)
    qf[s] = *(const bf16x8*)&qkv[(bS + wq0 + ql) * 1152 + h * 64 + s * 16 + hi * 8];

  bf16x8 vones;  // all-ones B-frag: D[q][*] = row-sum l[q] in every column
#pragma unroll
  for (int i = 0; i < 8; ++i) vones[i] = (short)0x3F80;

  f32x16 oacc[2] = {};  // [dhblk]: row q=(r&3)+8*(r>>2)+4*hi, col dh=dhblk*32+ql
  f32x16 lacc = {};     // same row layout as oacc

#define ATTN_STAGE(buf, kb)                                                     \
  {                                                                             \
    int s = wave; /* 8 waves -> 8 segments each of Ks and Vts */                \
    int rrow = s * 8 + segrow; /* key for Ks, dh for Vts */                     \
    int clog = cph ^ (rrow & 7);                                                \
    gload_lds16(qkv + (bS + (kb) + rrow) * 1152 + 1024 + clog * 8,              \
                (char*)&Ks[buf][0] + s * 1024);                                 \
    gload_lds16(vt + ((long)b * 64 + rrow) * Sx + (kb) + clog * 8,              \
                (char*)&Vts[buf][0] + s * 1024);                                \
  }

  const int kb_start = (q0 > 511) ? (q0 - 512) : 0;
  const int kb_end = q0 + 192;  // inclusive; covers keys up to q0+255
  ATTN_STAGE(0, kb_start);
  __syncthreads();  // drains prologue staging; also covers bias2S
  int cur = 0;
  for (int kb = kb_start; kb <= kb_end; kb += 64) {
    if (kb + 64 <= kb_end) ATTN_STAGE(cur ^ 1, kb + 64);
    const bool active = (kb <= wq0 + 31) && (kb + 63 >= wq0 - 511);
    if (active) {
      // S[key][q]: sacc[kblk] reg r -> key = kblk*32+(r&3)+8*(r>>2)+4*hi, q = ql
      f32x16 sacc[2] = {};
#pragma unroll
      for (int kblk = 0; kblk < 2; ++kblk) {
        int key = kblk * 32 + ql;
#pragma unroll
        for (int s = 0; s < 4; ++s) {
          int c = 2 * s + hi;
          bf16x8 kf = *(const bf16x8*)&Ks[cur][key * 64 + ((c ^ (key & 7)) << 3)];
          sacc[kblk] = __builtin_amdgcn_mfma_f32_32x32x16_bf16(kf, qf[s],
                                                               sacc[kblk], 0, 0, 0);
        }
      }
      // fixed-M softmax: p = exp2(qk*C1 + bias2[d]), d = q - j
      const int dbase = wq0 + ql - kb - 4 * hi;
      const bool full = (kb - wq0 >= -480) && (kb - wq0 <= -64);
      if (full) {
        const float* bpz = bias2S + dbase - 63;
#pragma unroll
        for (int kblk = 0; kblk < 2; ++kblk)
#pragma unroll
          for (int r = 0; r < 16; ++r) {
            const int off = kblk * 32 + (r & 3) + 8 * (r >> 2);
            sacc[kblk][r] = __builtin_exp2f(fmaf(sacc[kblk][r], C1, bpz[63 - off]));
          }
      } else {
#pragma unroll
        for (int kblk = 0; kblk < 2; ++kblk)
#pragma unroll
          for (int r = 0; r < 16; ++r) {
            const int off = kblk * 32 + (r & 3) + 8 * (r >> 2);
            int d = dbase - off;
            int dc = d < 0 ? 0 : (d > 511 ? 511 : d);
            float p = __builtin_exp2f(fmaf(sacc[kblk][r], C1, bias2S[dc]));
            sacc[kblk][r] = ((unsigned)d < 512u) ? p : 0.0f;
          }
      }
      // PV: per K-16 step, build A-frag in-register (cvt_pk + permlane32_swap)
#pragma unroll
      for (int s = 0; s < 4; ++s) {
        const int kblk = s >> 1;
        const int m0 = 2 * (s & 1);
        u32 a0 = cvt_pk_bf16(sacc[kblk][4 * m0 + 0], sacc[kblk][4 * m0 + 1]);
        u32 a1 = cvt_pk_bf16(sacc[kblk][4 * m0 + 2], sacc[kblk][4 * m0 + 3]);
        u32 b0 = cvt_pk_bf16(sacc[kblk][4 * m0 + 4], sacc[kblk][4 * m0 + 5]);
        u32 b1 = cvt_pk_bf16(sacc[kblk][4 * m0 + 6], sacc[kblk][4 * m0 + 7]);
        asm("v_permlane32_swap_b32 %0, %1" : "+v"(a0), "+v"(b0));
        asm("v_permlane32_swap_b32 %0, %1" : "+v"(a1), "+v"(b1));
        i32x4 t;
        t.x = (int)a0; t.y = (int)a1; t.z = (int)b0; t.w = (int)b1;
        bf16x8 pa = __builtin_bit_cast(bf16x8, t);
        lacc = __builtin_amdgcn_mfma_f32_32x32x16_bf16(pa, vones, lacc, 0, 0, 0);
#pragma unroll
        for (int dhblk = 0; dhblk < 2; ++dhblk) {
          int dh = dhblk * 32 + ql;
          int c = 2 * s + hi;
          bf16x8 vf = *(const bf16x8*)&Vts[cur][dh * 64 + ((c ^ (dh & 7)) << 3)];
          oacc[dhblk] = __builtin_amdgcn_mfma_f32_32x32x16_bf16(pa, vf,
                                                                oacc[dhblk], 0, 0, 0);
        }
      }
    }
    __syncthreads();  // drains next-chunk staging; protects buffers (WAR)
    cur ^= 1;
  }
#undef ATTN_STAGE
  // epilogue: out = O / l ; lacc rows match oacc rows exactly (no shuffle)
#pragma unroll
  for (int r = 0; r < 16; ++r) {
    const int q = (r & 3) + 8 * (r >> 2) + 4 * hi;
    float inv = 1.0f / lacc[r];
    long row = (bS + wq0 + q) * 1024 + h * 64;
#pragma unroll
    for (int dhblk = 0; dhblk < 2; ++dhblk)
      attnb[row + dhblk * 32 + ql] = f2b(oacc[dhblk][r] * inv);
  }
}

extern "C" void kernel_launch(void* const* d_in, const int* in_sizes, int n_in,
                              void* d_out, int out_size, void* d_ws, size_t ws_size,
                              hipStream_t stream) {
  const float* x    = (const float*)d_in[0];
  const float* bias = (const float*)d_in[1];
  const float* Wq   = (const float*)d_in[2];
  const float* Wk   = (const float*)d_in[3];
  const float* Wv   = (const float*)d_in[4];
  const float* Wo   = (const float*)d_in[5];
  float* out = (float*)d_out;

  // workspace layout (39.25 MB total); attnb ALIASES xb (xb dead after GEMM1)
  u16* xb    = (u16*)d_ws;                       // 8192x1024      (16 MB)
  u16* wcat  = xb    + (size_t)8192 * 1024;      // 1152x1024 (N,K) (2.25 MB)
  u16* wot   = wcat  + (size_t)1152 * 1024;      // 1024x1024 (N,K) (2 MB)
  u16* qkvb  = wot   + (size_t)1024 * 1024;      // 8192x1152      (18 MB)
  u16* vtb   = qkvb  + (size_t)8192 * 1152;      // 2x64x4096      (1 MB)
  u16* attnb = xb;                               // reuse xb       (16 MB)

  cast_x_kernel<<<8192, 256, 0, stream>>>(x, xb);
  pack_w_kernel<<<544, 256, 0, stream>>>(Wq, Wk, Wv, Wo, wcat, wot);
  gemm_bt_kernel<u16><<<dim3(64, 9), 256, 0, stream>>>(xb, wcat, qkvb, 8192, 1152, 1024);
  vt_transpose_kernel<<<128, 256, 0, stream>>>(qkvb, vtb);
  attn_kernel<<<512, 512, 0, stream>>>(qkvb, vtb, bias, attnb);
  gemm_bt_kernel<float><<<dim3(64, 8), 256, 0, stream>>>(attnb, wot, out, 8192, 1024, 1024);
}